// Round 3
// baseline (351.257 us; speedup 1.0000x reference)
//
#include <hip/hip_runtime.h>

// CrossAttentionGAT — algebraically collapsed; sort-free edge path via
// node-range-partitioned edge scan + LDS-privatized segment reduction.
//
// mean(cross1) = mean(emb2) @ Wl + bl   (softmax col-sums == 1)
// mean(cross2) = mean(emb1) @ Wl + bl   (softmax row-sums == 1)
// mean(emb)    = (1/N) * sum_k g[head,k] * W[k, head*C+c] + b
//   g[head,k]  = sum_n w[n,head] x[n,k],  w[n,head] = sum_{e: src=n} alpha_e[head]

#define NN 8192
#define EE 262144
#define NEG 0.2f

#define BSC 64            // blocks per graph for edge scans
#define RNG (NN / BSC)    // 128 nodes per block
#define QCAP 320          // per-wave queue capacity (>= QTHR-1 + 256 worst case)
#define QTHR 48

// ---------------- ws layout (4-byte units) ----------------
#define U_G     0                      // 2*1024 floats (zeroed)
#define U_MEMB  (U_G + 2048)           // 2*1024 floats (zeroed)
#define U_ZEND  (U_MEMB + 2048)
#define U_U     (U_ZEND)               // 2*2048 floats
#define U_ASRC  (U_U + 2*2048)         // 2*NN*8
#define U_ADST  (U_ASRC + 2*NN*8)      // 2*NN*8
#define U_PR    (U_ADST + 2*NN*8)      // 2*NN*16 floats: (adst, rden) float2 pairs
#define U_WACC  (U_PR + 2*NN*16)       // 2*NN*8
#define ZERO_BYTES ((size_t)U_ZEND * 4)

// K1: u[graph][sd][head][k] = att[head][:] . W[k][head*128:+128].
// One block per (graph,sd,head); wave per k-stripe, coalesced float2 loads.
__global__ __launch_bounds__(256) void k_u(
    const float* __restrict__ W1, const float* __restrict__ as1, const float* __restrict__ ad1,
    const float* __restrict__ W2, const float* __restrict__ as2, const float* __restrict__ ad2,
    float* __restrict__ u) {
  int b = blockIdx.x;                  // graph*16 + sd*8 + head
  int graph = b >> 4, sd = (b >> 3) & 1, head = b & 7;
  const float* W = graph ? W2 : W1;
  const float* att = graph ? (sd ? ad2 : as2) : (sd ? ad1 : as1);
  int w = threadIdx.x >> 6, lane = threadIdx.x & 63;
  float2 av = ((const float2*)(att + head * 128))[lane];
  float* uo = u + graph * 2048 + sd * 1024 + head * 128;
#pragma unroll 4
  for (int k = w; k < 128; k += 4) {
    float2 wv = ((const float2*)(W + (size_t)k * 1024 + head * 128))[lane];
    float p = av.x * wv.x + av.y * wv.y;
    p += __shfl_xor(p, 1);  p += __shfl_xor(p, 2);  p += __shfl_xor(p, 4);
    p += __shfl_xor(p, 8);  p += __shfl_xor(p, 16); p += __shfl_xor(p, 32);
    if (lane == 0) uo[k] = p;
  }
}

// K2: a_src[n,h] = x[n,:] . u_src[h,:] ; a_dst likewise. 64 nodes/block.
__global__ __launch_bounds__(256) void k_a(
    const float* __restrict__ x1, const float* __restrict__ x2,
    const float* __restrict__ u, float* __restrict__ asrc, float* __restrict__ adst) {
  int graph = blockIdx.y;
  const float* x = graph ? x2 : x1;
  const float* ug = u + graph * 2048;
  __shared__ float xs[64][129];
  __shared__ float us[16][128];
  int t = threadIdx.x;
  for (int i = t; i < 2048; i += 256) us[i >> 7][i & 127] = ug[i];
  int n0 = blockIdx.x * 64;
  const float* xb = x + (size_t)n0 * 128;
  for (int i = t; i < 64 * 128; i += 256) xs[i >> 7][i & 127] = xb[i];
  __syncthreads();
  int nl = t & 63;
  int j0 = (t >> 6) * 4;
  float a0 = 0.f, a1 = 0.f, a2 = 0.f, a3 = 0.f;
#pragma unroll 4
  for (int k = 0; k < 128; ++k) {
    float xv = xs[nl][k];
    a0 += xv * us[j0 + 0][k];
    a1 += xv * us[j0 + 1][k];
    a2 += xv * us[j0 + 2][k];
    a3 += xv * us[j0 + 3][k];
  }
  int n = n0 + nl;
  float* outp = (j0 < 8) ? (asrc + graph * (NN * 8) + n * 8 + j0)
                         : (adst + graph * (NN * 8) + n * 8 + (j0 - 8));
  outp[0] = a0; outp[1] = a1; outp[2] = a2; outp[3] = a3;
}

// K3: per 128-node dst-range: scan all dsts (int4, coalesced), queue matches,
// drain 8-lanes-per-edge into LDS den tile. Self-loops seed the tile.
// Output: pr[n] = (adst[n,h], 1/den[n,h]) as float2 pairs.
__global__ __launch_bounds__(512) void k_den_scan(
    const int* __restrict__ ei1, const int* __restrict__ ei2,
    const float* __restrict__ asrc, const float* __restrict__ adst,
    float* __restrict__ pr) {
  int g = blockIdx.y;
  const int* ei = g ? ei2 : ei1;
  const float* as = asrc + g * (NN * 8);
  const float* ad = adst + g * (NN * 8);
  float2* prg = (float2*)pr + (size_t)g * (NN * 8);
  int lo = blockIdx.x * RNG;
  __shared__ float den[RNG * 8];
  __shared__ float adsts[RNG * 8];
  __shared__ int q[8][QCAP];
  __shared__ int qn[8];
  int t = threadIdx.x;
  for (int i = t; i < RNG * 8; i += 512) {
    float avv = ad[lo * 8 + i];
    float v = as[lo * 8 + i] + avv;      // self loop: s == d
    v = v > 0.f ? v : NEG * v;
    adsts[i] = avv;
    den[i] = __expf(v);
  }
  if (t < 8) qn[t] = 0;
  __syncthreads();
  int w = t >> 6, lane = t & 63, h = lane & 7;
  const int4* d4p = (const int4*)(ei + EE);
  const int NIT = EE / 4 / 512;          // 128
  for (int it = 0; it < NIT; ++it) {
    int gi = it * 512 + w * 64 + lane;
    int4 d4 = d4p[gi];
    int e0 = gi * 4;
    unsigned r;
    r = (unsigned)(d4.x - lo); if (r < RNG) { int sl = atomicAdd(&qn[w], 1); q[w][sl] = ((e0 + 0) << 7) | r; }
    r = (unsigned)(d4.y - lo); if (r < RNG) { int sl = atomicAdd(&qn[w], 1); q[w][sl] = ((e0 + 1) << 7) | r; }
    r = (unsigned)(d4.z - lo); if (r < RNG) { int sl = atomicAdd(&qn[w], 1); q[w][sl] = ((e0 + 2) << 7) | r; }
    r = (unsigned)(d4.w - lo); if (r < RNG) { int sl = atomicAdd(&qn[w], 1); q[w][sl] = ((e0 + 3) << 7) | r; }
    int cnt = qn[w];
    if (cnt >= QTHR || it == NIT - 1) {
      for (int k0 = lane >> 3; k0 < cnt; k0 += 8) {
        int p = q[w][k0];
        int e = p >> 7, dl = p & (RNG - 1);
        int s = ei[e];
        float v = as[s * 8 + h] + adsts[dl * 8 + h];
        v = v > 0.f ? v : NEG * v;
        atomicAdd(&den[dl * 8 + h], __expf(v));
      }
      if (lane == 0) qn[w] = 0;
    }
  }
  __syncthreads();
  for (int i = t; i < RNG * 8; i += 512)
    prg[lo * 8 + i] = make_float2(adsts[i], 1.0f / den[i]);
}

// K4: per 128-node src-range: scan all srcs, drain gathers (adst,rden) float2
// per edge-dst, accumulate w[s,h] = sum exp(lrelu(..)) * rden[d,h] in LDS.
__global__ __launch_bounds__(512) void k_wacc_scan(
    const int* __restrict__ ei1, const int* __restrict__ ei2,
    const float* __restrict__ asrc, const float* __restrict__ pr,
    float* __restrict__ wacc) {
  int g = blockIdx.y;
  const int* ei = g ? ei2 : ei1;
  const float* as = asrc + g * (NN * 8);
  const float2* prg = (const float2*)pr + (size_t)g * (NN * 8);
  int lo = blockIdx.x * RNG;
  __shared__ float wv[RNG * 8];
  __shared__ float asrcs[RNG * 8];
  __shared__ int q[8][QCAP];
  __shared__ int qn[8];
  int t = threadIdx.x;
  for (int i = t; i < RNG * 8; i += 512) {
    float sv = as[lo * 8 + i];
    float2 f2 = prg[lo * 8 + i];         // (adst[n,h], rden[n,h])
    float v = sv + f2.x;                 // self loop
    v = v > 0.f ? v : NEG * v;
    asrcs[i] = sv;
    wv[i] = __expf(v) * f2.y;
  }
  if (t < 8) qn[t] = 0;
  __syncthreads();
  int w = t >> 6, lane = t & 63, h = lane & 7;
  const int4* s4p = (const int4*)ei;
  const int NIT = EE / 4 / 512;
  for (int it = 0; it < NIT; ++it) {
    int gi = it * 512 + w * 64 + lane;
    int4 s4 = s4p[gi];
    int e0 = gi * 4;
    unsigned r;
    r = (unsigned)(s4.x - lo); if (r < RNG) { int sl = atomicAdd(&qn[w], 1); q[w][sl] = ((e0 + 0) << 7) | r; }
    r = (unsigned)(s4.y - lo); if (r < RNG) { int sl = atomicAdd(&qn[w], 1); q[w][sl] = ((e0 + 1) << 7) | r; }
    r = (unsigned)(s4.z - lo); if (r < RNG) { int sl = atomicAdd(&qn[w], 1); q[w][sl] = ((e0 + 2) << 7) | r; }
    r = (unsigned)(s4.w - lo); if (r < RNG) { int sl = atomicAdd(&qn[w], 1); q[w][sl] = ((e0 + 3) << 7) | r; }
    int cnt = qn[w];
    if (cnt >= QTHR || it == NIT - 1) {
      for (int k0 = lane >> 3; k0 < cnt; k0 += 8) {
        int p = q[w][k0];
        int e = p >> 7, sl2 = p & (RNG - 1);
        int d = ei[EE + e];
        float2 f2 = prg[(size_t)d * 8 + h];
        float v = asrcs[sl2 * 8 + h] + f2.x;
        v = v > 0.f ? v : NEG * v;
        atomicAdd(&wv[sl2 * 8 + h], __expf(v) * f2.y);
      }
      if (lane == 0) qn[w] = 0;
    }
  }
  __syncthreads();
  for (int i = t; i < RNG * 8; i += 512)
    wacc[g * (NN * 8) + lo * 8 + i] = wv[i];
}

// K5: g[head,k] = sum_n w[n,head] * x[n,k].
#define GCHUNK 128
__global__ __launch_bounds__(256) void k_gred(
    const float* __restrict__ x1, const float* __restrict__ x2,
    const float* __restrict__ wacc, float* __restrict__ g) {
  int graph = blockIdx.y;
  const float* x = graph ? x2 : x1;
  const float* w = wacc + graph * (NN * 8);
  float* gg = g + graph * 1024;
  int t = threadIdx.x;
  int k = t & 127;
  int h0 = (t >> 7) * 4;
  int n0 = blockIdx.x * GCHUNK;
  float a0 = 0.f, a1 = 0.f, a2 = 0.f, a3 = 0.f;
#pragma unroll 4
  for (int n = n0; n < n0 + GCHUNK; ++n) {
    float xv = x[(size_t)n * 128 + k];
    float4 wv = *(const float4*)(w + (size_t)n * 8 + h0);
    a0 += xv * wv.x; a1 += xv * wv.y; a2 += xv * wv.z; a3 += xv * wv.w;
  }
  atomicAdd(gg + (h0 + 0) * 128 + k, a0);
  atomicAdd(gg + (h0 + 1) * 128 + k, a1);
  atomicAdd(gg + (h0 + 2) * 128 + k, a2);
  atomicAdd(gg + (h0 + 3) * 128 + k, a3);
}

// K6: memb[graph][e] += (1/N) * sum_{k in chunk} g[head,k]*W[k*1024+e] (+b at kc=0)
__global__ __launch_bounds__(256) void k_memb(
    const float* __restrict__ W1, const float* __restrict__ W2,
    const float* __restrict__ b1, const float* __restrict__ b2,
    const float* __restrict__ g, float* __restrict__ memb) {
  int graph = blockIdx.z;
  int kc = blockIdx.y;
  const float* W = graph ? W2 : W1;
  const float* b = graph ? b2 : b1;
  int e = blockIdx.x * 256 + threadIdx.x;
  int head = e >> 7;
  const float* gr = g + graph * 1024 + head * 128;
  float s = 0.f;
#pragma unroll
  for (int k = kc * 16; k < kc * 16 + 16; ++k) s += gr[k] * W[(size_t)k * 1024 + e];
  s *= (1.0f / (float)NN);
  if (kc == 0) s += b[e];
  atomicAdd(memb + graph * 1024 + e, s);
}

// K7: out = [memb(g1); memb(g0)] @ Wl + bl, split-k over 32 blocks (out pre-zeroed).
__global__ __launch_bounds__(256) void k_out(
    const float* __restrict__ memb, const float* __restrict__ Wl,
    const float* __restrict__ bl, float* __restrict__ out) {
  int t = threadIdx.x;
  int j = t & 127;
  int k0 = blockIdx.x * 32;
  const float* m = (t < 128) ? (memb + 1024) : memb;
  float s = 0.f;
#pragma unroll
  for (int k = k0; k < k0 + 32; ++k) s += m[k] * Wl[(size_t)k * 128 + j];
  if (blockIdx.x == 0) s += bl[j];
  atomicAdd(out + t, s);
}

extern "C" void kernel_launch(void* const* d_in, const int* in_sizes, int n_in,
                              void* d_out, int out_size, void* d_ws, size_t ws_size,
                              hipStream_t stream) {
  const float* x1  = (const float*)d_in[0];
  const int*   ei1 = (const int*)d_in[1];
  const float* W1  = (const float*)d_in[2];
  const float* as1 = (const float*)d_in[3];
  const float* ad1 = (const float*)d_in[4];
  const float* b1  = (const float*)d_in[5];
  const float* x2  = (const float*)d_in[6];
  const int*   ei2 = (const int*)d_in[7];
  const float* W2  = (const float*)d_in[8];
  const float* as2 = (const float*)d_in[9];
  const float* ad2 = (const float*)d_in[10];
  const float* b2  = (const float*)d_in[11];
  const float* Wl  = (const float*)d_in[12];
  const float* bl  = (const float*)d_in[13];
  float* out = (float*)d_out;

  float* g    = (float*)d_ws + U_G;
  float* memb = (float*)d_ws + U_MEMB;
  float* u    = (float*)d_ws + U_U;
  float* asrc = (float*)d_ws + U_ASRC;
  float* adst = (float*)d_ws + U_ADST;
  float* pr   = (float*)d_ws + U_PR;
  float* wacc = (float*)d_ws + U_WACC;

  hipMemsetAsync(d_ws, 0, ZERO_BYTES, stream);             // g + memb
  hipMemsetAsync(d_out, 0, (size_t)out_size * 4, stream);  // split-k target

  k_u<<<32, 256, 0, stream>>>(W1, as1, ad1, W2, as2, ad2, u);
  k_a<<<dim3(NN / 64, 2), 256, 0, stream>>>(x1, x2, u, asrc, adst);
  k_den_scan<<<dim3(BSC, 2), 512, 0, stream>>>(ei1, ei2, asrc, adst, pr);
  k_wacc_scan<<<dim3(BSC, 2), 512, 0, stream>>>(ei1, ei2, asrc, pr, wacc);
  k_gred<<<dim3(NN / GCHUNK, 2), 256, 0, stream>>>(x1, x2, wacc, g);
  k_memb<<<dim3(4, 8, 2), 256, 0, stream>>>(W1, W2, b1, b2, g, memb);
  k_out<<<32, 256, 0, stream>>>(memb, Wl, bl, out);
}

// Round 4
// 190.256 us; speedup vs baseline: 1.8462x; 1.8462x over previous
//
#include <hip/hip_runtime.h>

// CrossAttentionGAT — algebraically collapsed; edge path = coarse counting-bin
// (128 buckets of 64 nodes) + LDS-privatized per-bucket segment reduction.
//
// mean(cross1) = mean(emb2) @ Wl + bl   (softmax col-sums == 1)
// mean(cross2) = mean(emb1) @ Wl + bl   (softmax row-sums == 1)
// mean(emb)    = (1/N) * sum_k g[head,k] * W[k, head*C+c] + b
//   g[head,k]  = sum_n w[n,head] x[n,k],  w[n,head] = sum_{e: src=n} alpha_e[head]

#define NN 8192
#define EE 262144
#define NEG 0.2f

#define BKT 128           // node buckets per graph
#define RNG (NN / BKT)    // 64 nodes per bucket
#define CAP 2560          // bucket capacity: mean 2048 + 11 sigma
#define EB  128           // bin blocks per graph
#define CHK (EE / EB)     // 2048 edges per bin block

// ---------------- ws layout (4-byte units) ----------------
#define U_CNT   0                        // 2 graphs x {D,S} x BKT ints (zeroed)
#define U_G     (U_CNT + 4*BKT)          // 2*1024 floats (zeroed)
#define U_MEMB  (U_G + 2048)             // 2*1024 floats (zeroed)
#define U_ZEND  (U_MEMB + 2048)
#define U_U     (U_ZEND)                 // 2*2048 floats
#define U_ASRC  (U_U + 2*2048)           // 2*NN*8 floats
#define U_ADST  (U_ASRC + 2*NN*8)        // 2*NN*8 floats
#define U_PR    (U_ADST + 2*NN*8)        // 2*NN*16 floats: (adst,rden) float2
#define U_WACC  (U_PR + 2*NN*16)         // 2*NN*8 floats
#define U_BIND  (U_WACC + 2*NN*8)        // 2*BKT*CAP ints
#define U_BINS  (U_BIND + 2*BKT*CAP)     // 2*BKT*CAP ints
#define ZERO_BYTES ((size_t)U_ZEND * 4)

// K1: u[graph][sd][head][k] = att[head][:] . W[k][head*128:+128]
__global__ __launch_bounds__(256) void k_u(
    const float* __restrict__ W1, const float* __restrict__ as1, const float* __restrict__ ad1,
    const float* __restrict__ W2, const float* __restrict__ as2, const float* __restrict__ ad2,
    float* __restrict__ u) {
  int b = blockIdx.x;                  // graph*16 + sd*8 + head
  int graph = b >> 4, sd = (b >> 3) & 1, head = b & 7;
  const float* W = graph ? W2 : W1;
  const float* att = graph ? (sd ? ad2 : as2) : (sd ? ad1 : as1);
  int w = threadIdx.x >> 6, lane = threadIdx.x & 63;
  float2 av = ((const float2*)(att + head * 128))[lane];
  float* uo = u + graph * 2048 + sd * 1024 + head * 128;
#pragma unroll 4
  for (int k = w; k < 128; k += 4) {
    float2 wv = ((const float2*)(W + (size_t)k * 1024 + head * 128))[lane];
    float p = av.x * wv.x + av.y * wv.y;
    p += __shfl_xor(p, 1);  p += __shfl_xor(p, 2);  p += __shfl_xor(p, 4);
    p += __shfl_xor(p, 8);  p += __shfl_xor(p, 16); p += __shfl_xor(p, 32);
    if (lane == 0) uo[k] = p;
  }
}

// K2: a_src[n,h] = x[n,:] . u_src[h,:] ; a_dst likewise. 64 nodes/block.
__global__ __launch_bounds__(256) void k_a(
    const float* __restrict__ x1, const float* __restrict__ x2,
    const float* __restrict__ u, float* __restrict__ asrc, float* __restrict__ adst) {
  int graph = blockIdx.y;
  const float* x = graph ? x2 : x1;
  const float* ug = u + graph * 2048;
  __shared__ float xs[64][129];
  __shared__ float us[16][128];
  int t = threadIdx.x;
  for (int i = t; i < 2048; i += 256) us[i >> 7][i & 127] = ug[i];
  int n0 = blockIdx.x * 64;
  const float* xb = x + (size_t)n0 * 128;
  for (int i = t; i < 64 * 128; i += 256) xs[i >> 7][i & 127] = xb[i];
  __syncthreads();
  int nl = t & 63;
  int j0 = (t >> 6) * 4;
  float a0 = 0.f, a1 = 0.f, a2 = 0.f, a3 = 0.f;
#pragma unroll 4
  for (int k = 0; k < 128; ++k) {
    float xv = xs[nl][k];
    a0 += xv * us[j0 + 0][k];
    a1 += xv * us[j0 + 1][k];
    a2 += xv * us[j0 + 2][k];
    a3 += xv * us[j0 + 3][k];
  }
  int n = n0 + nl;
  float* outp = (j0 < 8) ? (asrc + graph * (NN * 8) + n * 8 + j0)
                         : (adst + graph * (NN * 8) + n * 8 + (j0 - 8));
  outp[0] = a0; outp[1] = a1; outp[2] = a2; outp[3] = a3;
}

// K3: bin edges by dst-bucket (payload s<<6|d%64) and src-bucket (d<<6|s%64).
// Per-block LDS histogram -> one reserve atomic per (block,bucket) -> write.
__global__ __launch_bounds__(512) void k_bin(
    const int* __restrict__ ei1, const int* __restrict__ ei2,
    int* __restrict__ cnt, int* __restrict__ binD, int* __restrict__ binS) {
  int g = blockIdx.y;
  const int* ei = g ? ei2 : ei1;
  __shared__ int hD[BKT], hS[BKT], bD[BKT], bS[BKT], cD[BKT], cS[BKT];
  int t = threadIdx.x;
  for (int i = t; i < BKT; i += 512) { hD[i] = 0; hS[i] = 0; cD[i] = 0; cS[i] = 0; }
  __syncthreads();
  int e0 = blockIdx.x * CHK;
  for (int i = t; i < CHK; i += 512) {
    int s = ei[e0 + i], d = ei[EE + e0 + i];
    atomicAdd(&hD[d >> 6], 1);
    atomicAdd(&hS[s >> 6], 1);
  }
  __syncthreads();
  for (int i = t; i < BKT; i += 512) {
    bD[i] = atomicAdd(cnt + (2 * g + 0) * BKT + i, hD[i]);
    bS[i] = atomicAdd(cnt + (2 * g + 1) * BKT + i, hS[i]);
  }
  __syncthreads();
  int* bdg = binD + (size_t)g * BKT * CAP;
  int* bsg = binS + (size_t)g * BKT * CAP;
  for (int i = t; i < CHK; i += 512) {
    int s = ei[e0 + i], d = ei[EE + e0 + i];
    int kb = d >> 6;
    int p = bD[kb] + atomicAdd(&cD[kb], 1);
    bdg[kb * CAP + p] = (s << 6) | (d & 63);
    kb = s >> 6;
    p = bS[kb] + atomicAdd(&cS[kb], 1);
    bsg[kb * CAP + p] = (d << 6) | (s & 63);
  }
}

// K4: per dst-bucket: den[dl,h] = selfloop + sum exp(lrelu(asrc[s]+adst[d])).
// 8 lanes per record (h = lane&7); LDS float atomics; out pr = (adst, 1/den).
__global__ __launch_bounds__(512) void k_den_red(
    const int* __restrict__ cnt, const int* __restrict__ binD,
    const float* __restrict__ asrc, const float* __restrict__ adst,
    float* __restrict__ pr) {
  int g = blockIdx.y, b = blockIdx.x;
  int lo = b * RNG;
  const float* as = asrc + g * (NN * 8);
  const float* ad = adst + g * (NN * 8);
  float2* prg = (float2*)pr + (size_t)g * (NN * 8);
  __shared__ float den[RNG * 8];
  __shared__ float adsts[RNG * 8];
  int t = threadIdx.x;
  for (int i = t; i < RNG * 8; i += 512) {
    float avv = ad[lo * 8 + i];
    float v = as[lo * 8 + i] + avv;      // self loop (s == d)
    v = v > 0.f ? v : NEG * v;
    adsts[i] = avv;
    den[i] = __expf(v);
  }
  __syncthreads();
  int n = cnt[(2 * g + 0) * BKT + b];
  const int* recs = binD + (size_t)g * BKT * CAP + b * CAP;
  int rid = t >> 3, h = t & 7;
  for (int base = 0; base < n; base += 256) {
    int rv[4]; bool ok[4]; float sv[4];
#pragma unroll
    for (int uu = 0; uu < 4; ++uu) {
      int i = base + uu * 64 + rid;
      ok[uu] = i < n;
      rv[uu] = ok[uu] ? recs[i] : 0;
    }
#pragma unroll
    for (int uu = 0; uu < 4; ++uu)
      sv[uu] = ok[uu] ? as[(rv[uu] >> 6) * 8 + h] : 0.f;
#pragma unroll
    for (int uu = 0; uu < 4; ++uu) {
      if (ok[uu]) {
        int dl = rv[uu] & 63;
        float v = sv[uu] + adsts[dl * 8 + h];
        v = v > 0.f ? v : NEG * v;
        atomicAdd(&den[dl * 8 + h], __expf(v));
      }
    }
  }
  __syncthreads();
  for (int i = t; i < RNG * 8; i += 512)
    prg[lo * 8 + i] = make_float2(adsts[i], 1.0f / den[i]);
}

// K5: per src-bucket: w[sl,h] = selfloop + sum exp(lrelu(asrc[s]+adst[d]))*rden[d].
__global__ __launch_bounds__(512) void k_wacc_red(
    const int* __restrict__ cnt, const int* __restrict__ binS,
    const float* __restrict__ asrc, const float* __restrict__ pr,
    float* __restrict__ wacc) {
  int g = blockIdx.y, b = blockIdx.x;
  int lo = b * RNG;
  const float* as = asrc + g * (NN * 8);
  const float2* prg = (const float2*)pr + (size_t)g * (NN * 8);
  __shared__ float wv[RNG * 8];
  __shared__ float asrcs[RNG * 8];
  int t = threadIdx.x;
  for (int i = t; i < RNG * 8; i += 512) {
    float sva = as[lo * 8 + i];
    float2 f2 = prg[lo * 8 + i];         // (adst[n,h], rden[n,h])
    float v = sva + f2.x;                // self loop
    v = v > 0.f ? v : NEG * v;
    asrcs[i] = sva;
    wv[i] = __expf(v) * f2.y;
  }
  __syncthreads();
  int n = cnt[(2 * g + 1) * BKT + b];
  const int* recs = binS + (size_t)g * BKT * CAP + b * CAP;
  int rid = t >> 3, h = t & 7;
  for (int base = 0; base < n; base += 256) {
    int rv[4]; bool ok[4]; float2 pv[4];
#pragma unroll
    for (int uu = 0; uu < 4; ++uu) {
      int i = base + uu * 64 + rid;
      ok[uu] = i < n;
      rv[uu] = ok[uu] ? recs[i] : 0;
    }
#pragma unroll
    for (int uu = 0; uu < 4; ++uu)
      pv[uu] = ok[uu] ? prg[(size_t)(rv[uu] >> 6) * 8 + h] : make_float2(0.f, 0.f);
#pragma unroll
    for (int uu = 0; uu < 4; ++uu) {
      if (ok[uu]) {
        int sl = rv[uu] & 63;
        float v = asrcs[sl * 8 + h] + pv[uu].x;
        v = v > 0.f ? v : NEG * v;
        atomicAdd(&wv[sl * 8 + h], __expf(v) * pv[uu].y);
      }
    }
  }
  __syncthreads();
  for (int i = t; i < RNG * 8; i += 512)
    wacc[g * (NN * 8) + lo * 8 + i] = wv[i];
}

// K6: g[head,k] = sum_n w[n,head] * x[n,k].
#define GCHUNK 128
__global__ __launch_bounds__(256) void k_gred(
    const float* __restrict__ x1, const float* __restrict__ x2,
    const float* __restrict__ wacc, float* __restrict__ g) {
  int graph = blockIdx.y;
  const float* x = graph ? x2 : x1;
  const float* w = wacc + graph * (NN * 8);
  float* gg = g + graph * 1024;
  int t = threadIdx.x;
  int k = t & 127;
  int h0 = (t >> 7) * 4;
  int n0 = blockIdx.x * GCHUNK;
  float a0 = 0.f, a1 = 0.f, a2 = 0.f, a3 = 0.f;
#pragma unroll 4
  for (int n = n0; n < n0 + GCHUNK; ++n) {
    float xv = x[(size_t)n * 128 + k];
    float4 wv4 = *(const float4*)(w + (size_t)n * 8 + h0);
    a0 += xv * wv4.x; a1 += xv * wv4.y; a2 += xv * wv4.z; a3 += xv * wv4.w;
  }
  atomicAdd(gg + (h0 + 0) * 128 + k, a0);
  atomicAdd(gg + (h0 + 1) * 128 + k, a1);
  atomicAdd(gg + (h0 + 2) * 128 + k, a2);
  atomicAdd(gg + (h0 + 3) * 128 + k, a3);
}

// K7: memb[graph][e] += (1/N) * sum_{k chunk} g[head,k]*W[k*1024+e] (+b at kc=0)
__global__ __launch_bounds__(256) void k_memb(
    const float* __restrict__ W1, const float* __restrict__ W2,
    const float* __restrict__ b1, const float* __restrict__ b2,
    const float* __restrict__ g, float* __restrict__ memb) {
  int graph = blockIdx.z;
  int kc = blockIdx.y;
  const float* W = graph ? W2 : W1;
  const float* b = graph ? b2 : b1;
  int e = blockIdx.x * 256 + threadIdx.x;
  int head = e >> 7;
  const float* gr = g + graph * 1024 + head * 128;
  float s = 0.f;
#pragma unroll
  for (int k = kc * 16; k < kc * 16 + 16; ++k) s += gr[k] * W[(size_t)k * 1024 + e];
  s *= (1.0f / (float)NN);
  if (kc == 0) s += b[e];
  atomicAdd(memb + graph * 1024 + e, s);
}

// K8: out = [memb(g1); memb(g0)] @ Wl + bl, split-k over 32 blocks (out zeroed).
__global__ __launch_bounds__(256) void k_out(
    const float* __restrict__ memb, const float* __restrict__ Wl,
    const float* __restrict__ bl, float* __restrict__ out) {
  int t = threadIdx.x;
  int j = t & 127;
  int k0 = blockIdx.x * 32;
  const float* m = (t < 128) ? (memb + 1024) : memb;
  float s = 0.f;
#pragma unroll
  for (int k = k0; k < k0 + 32; ++k) s += m[k] * Wl[(size_t)k * 128 + j];
  if (blockIdx.x == 0) s += bl[j];
  atomicAdd(out + t, s);
}

extern "C" void kernel_launch(void* const* d_in, const int* in_sizes, int n_in,
                              void* d_out, int out_size, void* d_ws, size_t ws_size,
                              hipStream_t stream) {
  const float* x1  = (const float*)d_in[0];
  const int*   ei1 = (const int*)d_in[1];
  const float* W1  = (const float*)d_in[2];
  const float* as1 = (const float*)d_in[3];
  const float* ad1 = (const float*)d_in[4];
  const float* b1  = (const float*)d_in[5];
  const float* x2  = (const float*)d_in[6];
  const int*   ei2 = (const int*)d_in[7];
  const float* W2  = (const float*)d_in[8];
  const float* as2 = (const float*)d_in[9];
  const float* ad2 = (const float*)d_in[10];
  const float* b2  = (const float*)d_in[11];
  const float* Wl  = (const float*)d_in[12];
  const float* bl  = (const float*)d_in[13];
  float* out = (float*)d_out;

  int*   cnt  = (int*)d_ws + U_CNT;
  float* g    = (float*)d_ws + U_G;
  float* memb = (float*)d_ws + U_MEMB;
  float* u    = (float*)d_ws + U_U;
  float* asrc = (float*)d_ws + U_ASRC;
  float* adst = (float*)d_ws + U_ADST;
  float* pr   = (float*)d_ws + U_PR;
  float* wacc = (float*)d_ws + U_WACC;
  int*   binD = (int*)d_ws + U_BIND;
  int*   binS = (int*)d_ws + U_BINS;

  hipMemsetAsync(d_ws, 0, ZERO_BYTES, stream);             // cnt + g + memb
  hipMemsetAsync(d_out, 0, (size_t)out_size * 4, stream);  // split-k target

  k_bin<<<dim3(EB, 2), 512, 0, stream>>>(ei1, ei2, cnt, binD, binS);
  k_u<<<32, 256, 0, stream>>>(W1, as1, ad1, W2, as2, ad2, u);
  k_a<<<dim3(NN / 64, 2), 256, 0, stream>>>(x1, x2, u, asrc, adst);
  k_den_red<<<dim3(BKT, 2), 512, 0, stream>>>(cnt, binD, asrc, adst, pr);
  k_wacc_red<<<dim3(BKT, 2), 512, 0, stream>>>(cnt, binS, asrc, pr, wacc);
  k_gred<<<dim3(NN / GCHUNK, 2), 256, 0, stream>>>(x1, x2, wacc, g);
  k_memb<<<dim3(4, 8, 2), 256, 0, stream>>>(W1, W2, b1, b2, g, memb);
  k_out<<<32, 256, 0, stream>>>(memb, Wl, bl, out);
}